// Round 1
// 334.755 us; speedup vs baseline: 1.0672x; 1.0672x over previous
//
#include <hip/hip_runtime.h>

// QuantumLayer: h = x @ W + b  (B x 1024 @ 1024 x 2), row-normalize h,
// then a fixed 2-qubit circuit -> [B,2] <Z> values.
// HBM-read-bound on x (256 MiB, read exactly once). One wave per 8 rows.
//
// R1 change vs previous best (357 us): software-pipeline row-pairs
// (prefetch next pair's 8x16B loads before the shfl-reduce/circuit tail),
// remove per-pair bounds guards on the exactly-covered fast path, and use
// nontemporal loads for the single-use x stream. Diagnostic: if dur_us is
// unchanged, the kernel is at the HBM floor and the residual 320 us is
// harness poison-fill traffic (2x 1 GiB fills at ~161 us each).

#define WAVES_PER_BLOCK 4
#define ROWS_PER_WAVE   8
#define ROWS_PER_BLOCK  (WAVES_PER_BLOCK * ROWS_PER_WAVE)

typedef float f4 __attribute__((ext_vector_type(4)));

__device__ __forceinline__ f4 ld_nt(const f4* p) {
    return __builtin_nontemporal_load(p);
}

__device__ __forceinline__ float2 run_circuit(float h0, float h1,
                                              const float cw[2][2],
                                              const float sw[2][2]) {
    // normalize (h0,h1) to unit norm, angles theta/2
    float inv = rsqrtf(fmaxf(h0 * h0 + h1 * h1, 1e-12f));
    float s0, c0, s1, c1;
    __sincosf(0.5f * h0 * inv, &s0, &c0);
    __sincosf(0.5f * h1 * inv, &s1, &c1);

    // State after RX(h0) wire0, RX(h1) wire1 applied to |00>, hand-expanded:
    // s00 = c0*c1 ; s01 = -i*c0*s1 ; s10 = -i*s0*c1 ; s11 = -s0*s1
    float re[2][2], im[2][2];
    re[0][0] = c0 * c1;  im[0][0] = 0.0f;
    re[0][1] = 0.0f;     im[0][1] = -c0 * s1;
    re[1][0] = 0.0f;     im[1][0] = -s0 * c1;
    re[1][1] = -s0 * s1; im[1][1] = 0.0f;

#pragma unroll
    for (int l = 0; l < 2; ++l) {
        // RX on wire 0 (first index)
        {
            float c = cw[l][0], s = sw[l][0];
#pragma unroll
            for (int k = 0; k < 2; ++k) {
                float ar = re[0][k], ai = im[0][k];
                float br = re[1][k], bi = im[1][k];
                re[0][k] = c * ar + s * bi;
                im[0][k] = c * ai - s * br;
                re[1][k] = s * ai + c * br;
                im[1][k] = c * bi - s * ar;
            }
        }
        // RX on wire 1 (second index)
        {
            float c = cw[l][1], s = sw[l][1];
#pragma unroll
            for (int k = 0; k < 2; ++k) {
                float ar = re[k][0], ai = im[k][0];
                float br = re[k][1], bi = im[k][1];
                re[k][0] = c * ar + s * bi;
                im[k][0] = c * ai - s * br;
                re[k][1] = s * ai + c * br;
                im[k][1] = c * bi - s * ar;
            }
        }
        // CNOT(0 -> 1): swap s10 <-> s11
        {
            float tr = re[1][0], ti = im[1][0];
            re[1][0] = re[1][1]; im[1][0] = im[1][1];
            re[1][1] = tr;       im[1][1] = ti;
        }
    }

    float p00 = re[0][0] * re[0][0] + im[0][0] * im[0][0];
    float p01 = re[0][1] * re[0][1] + im[0][1] * im[0][1];
    float p10 = re[1][0] * re[1][0] + im[1][0] * im[1][0];
    float p11 = re[1][1] * re[1][1] + im[1][1] * im[1][1];

    float2 z;
    z.x = (p00 + p01) - (p10 + p11);
    z.y = (p00 + p10) - (p01 + p11);
    return z;
}

__global__ __launch_bounds__(256) void qlayer_kernel(
    const float* __restrict__ x,    // [B,1024]
    const float* __restrict__ w,    // [1024,2] row-major: w[d*2+q]
    const float* __restrict__ bias, // [2]
    const float* __restrict__ wq,   // [2,2]
    float* __restrict__ out,        // [B,2]
    int B)
{
    const int lane = threadIdx.x & 63;
    const int wave = threadIdx.x >> 6;
    const int rowBase = (blockIdx.x * WAVES_PER_BLOCK + wave) * ROWS_PER_WAVE;
    if (rowBase >= B) return;

    // Preload this lane's weight fragments: lane handles float4-indices
    // f = lane + 64*j (j=0..3) of the 256-float4 row; w fragment for d=4f
    // is 8 consecutive floats = two float4 at indices 2f, 2f+1.
    const f4* __restrict__ w4 = (const f4*)w;
    f4 wA[4], wB[4];
#pragma unroll
    for (int j = 0; j < 4; ++j) {
        int f = lane + 64 * j;
        wA[j] = w4[2 * f];
        wB[j] = w4[2 * f + 1];
    }

    const float b0 = bias[0], b1 = bias[1];

    // Per-layer RX angle sin/cos (constant across rows)
    float cw[2][2], sw[2][2];
#pragma unroll
    for (int l = 0; l < 2; ++l) {
#pragma unroll
        for (int q = 0; q < 2; ++q) {
            float t = 0.5f * wq[l * 2 + q];
            __sincosf(t, &sw[l][q], &cw[l][q]);
        }
    }

    float2* __restrict__ out2 = (float2*)out;
    const f4* __restrict__ x4 = (const f4*)x;

    if (rowBase + ROWS_PER_WAVE <= B) {
        // ---- fast path: all 8 rows valid; software-pipelined pairs ----
        f4 va[4], vb[4];   // current pair (rows 2r, 2r+1)
        f4 pa[4], pb[4];   // prefetch pair (rows 2r+2, 2r+3)

        {
            const f4* __restrict__ xp = x4 + (size_t)rowBase * 256;
#pragma unroll
            for (int j = 0; j < 4; ++j) {
                const int f = lane + 64 * j;
                va[j] = ld_nt(xp + f);
                vb[j] = ld_nt(xp + 256 + f);
            }
        }

#pragma unroll
        for (int r = 0; r < ROWS_PER_WAVE / 2; ++r) {
            // Issue next pair's loads BEFORE the reduce/circuit tail so the
            // memory pipe stays busy through the dependent shuffle chain.
            if (r + 1 < ROWS_PER_WAVE / 2) {
                const f4* __restrict__ xp =
                    x4 + (size_t)(rowBase + 2 * (r + 1)) * 256;
#pragma unroll
                for (int j = 0; j < 4; ++j) {
                    const int f = lane + 64 * j;
                    pa[j] = ld_nt(xp + f);
                    pb[j] = ld_nt(xp + 256 + f);
                }
            }

            float a0 = 0.f, a1 = 0.f, c0s = 0.f, c1s = 0.f;
#pragma unroll
            for (int j = 0; j < 4; ++j) {
                f4 vA = va[j];
                f4 vB = vb[j];
                a0 = fmaf(vA.x, wA[j].x, a0); a1 = fmaf(vA.x, wA[j].y, a1);
                a0 = fmaf(vA.y, wA[j].z, a0); a1 = fmaf(vA.y, wA[j].w, a1);
                a0 = fmaf(vA.z, wB[j].x, a0); a1 = fmaf(vA.z, wB[j].y, a1);
                a0 = fmaf(vA.w, wB[j].z, a0); a1 = fmaf(vA.w, wB[j].w, a1);
                c0s = fmaf(vB.x, wA[j].x, c0s); c1s = fmaf(vB.x, wA[j].y, c1s);
                c0s = fmaf(vB.y, wA[j].z, c0s); c1s = fmaf(vB.y, wA[j].w, c1s);
                c0s = fmaf(vB.z, wB[j].x, c0s); c1s = fmaf(vB.z, wB[j].y, c1s);
                c0s = fmaf(vB.w, wB[j].z, c0s); c1s = fmaf(vB.w, wB[j].w, c1s);
            }

            // butterfly reduce across the 64-lane wave
#pragma unroll
            for (int off = 32; off >= 1; off >>= 1) {
                a0  += __shfl_xor(a0, off, 64);
                a1  += __shfl_xor(a1, off, 64);
                c0s += __shfl_xor(c0s, off, 64);
                c1s += __shfl_xor(c1s, off, 64);
            }

            float2 zA = run_circuit(a0 + b0, a1 + b1, cw, sw);
            float2 zB = run_circuit(c0s + b0, c1s + b1, cw, sw);

            if (lane == 0) {
                out2[rowBase + 2 * r]     = zA;
                out2[rowBase + 2 * r + 1] = zB;
            }

            if (r + 1 < ROWS_PER_WAVE / 2) {
#pragma unroll
                for (int j = 0; j < 4; ++j) { va[j] = pa[j]; vb[j] = pb[j]; }
            }
        }
    } else {
        // ---- tail path: guarded, non-pipelined (taken only if B % 32 != 0) ----
#pragma unroll
        for (int r = 0; r < ROWS_PER_WAVE; r += 2) {
            const int rowA = rowBase + r;
            if (rowA >= B) break;
            const int rowB = rowA + 1;
            const bool hasB = (rowB < B);

            const f4* __restrict__ xA = x4 + (size_t)rowA * 256;
            const f4* __restrict__ xB = x4 + (size_t)(hasB ? rowB : rowA) * 256;

            float a0 = 0.f, a1 = 0.f, c0s = 0.f, c1s = 0.f;
#pragma unroll
            for (int j = 0; j < 4; ++j) {
                const int f = lane + 64 * j;
                f4 vA = xA[f];
                f4 vB = xB[f];
                a0 = fmaf(vA.x, wA[j].x, a0); a1 = fmaf(vA.x, wA[j].y, a1);
                a0 = fmaf(vA.y, wA[j].z, a0); a1 = fmaf(vA.y, wA[j].w, a1);
                a0 = fmaf(vA.z, wB[j].x, a0); a1 = fmaf(vA.z, wB[j].y, a1);
                a0 = fmaf(vA.w, wB[j].z, a0); a1 = fmaf(vA.w, wB[j].w, a1);
                c0s = fmaf(vB.x, wA[j].x, c0s); c1s = fmaf(vB.x, wA[j].y, c1s);
                c0s = fmaf(vB.y, wA[j].z, c0s); c1s = fmaf(vB.y, wA[j].w, c1s);
                c0s = fmaf(vB.z, wB[j].x, c0s); c1s = fmaf(vB.z, wB[j].y, c1s);
                c0s = fmaf(vB.w, wB[j].z, c0s); c1s = fmaf(vB.w, wB[j].w, c1s);
            }

#pragma unroll
            for (int off = 32; off >= 1; off >>= 1) {
                a0  += __shfl_xor(a0, off, 64);
                a1  += __shfl_xor(a1, off, 64);
                c0s += __shfl_xor(c0s, off, 64);
                c1s += __shfl_xor(c1s, off, 64);
            }

            float2 zA = run_circuit(a0 + b0, a1 + b1, cw, sw);
            float2 zB = run_circuit(c0s + b0, c1s + b1, cw, sw);

            if (lane == 0) {
                out2[rowA] = zA;
                if (hasB) out2[rowB] = zB;
            }
        }
    }
}

extern "C" void kernel_launch(void* const* d_in, const int* in_sizes, int n_in,
                              void* d_out, int out_size, void* d_ws, size_t ws_size,
                              hipStream_t stream) {
    const float* x    = (const float*)d_in[0];
    const float* w    = (const float*)d_in[1];
    const float* bias = (const float*)d_in[2];
    const float* wq   = (const float*)d_in[3];
    float* out = (float*)d_out;

    const int B = in_sizes[0] / 1024;
    const int grid = (B + ROWS_PER_BLOCK - 1) / ROWS_PER_BLOCK;
    qlayer_kernel<<<grid, 256, 0, stream>>>(x, w, bias, wq, out, B);
}